// Round 7
// baseline (12418.963 us; speedup 1.0000x reference)
//
#include <hip/hip_runtime.h>
#include <hip/hip_bf16.h>
#include <cstdint>
#include <cstddef>

#define BB 64
#define TT 512
#define DD 1024
#define HH 2048
#define GG 8192   // 4*H

typedef unsigned short u16;
typedef __attribute__((ext_vector_type(8))) short bf16x8;
typedef __attribute__((ext_vector_type(4))) float f32x4;

__device__ __forceinline__ u16 f2bf(float f) {
  union { float f; uint32_t u; } v; v.f = f;
  uint32_t r = v.u + 0x7FFFu + ((v.u >> 16) & 1u);  // RNE
  return (u16)(r >> 16);
}
__device__ __forceinline__ float bf2f(u16 h) {
  union { uint32_t u; float f; } v; v.u = ((uint32_t)h) << 16; return v.f;
}

__device__ __forceinline__ bf16x8 cvt8(const float* __restrict__ p) {
  float4 a = *(const float4*)p;
  float4 b = *(const float4*)(p + 4);
  bf16x8 r;
  r[0] = (short)f2bf(a.x); r[1] = (short)f2bf(a.y);
  r[2] = (short)f2bf(a.z); r[3] = (short)f2bf(a.w);
  r[4] = (short)f2bf(b.x); r[5] = (short)f2bf(b.y);
  r[6] = (short)f2bf(b.z); r[7] = (short)f2bf(b.w);
  return r;
}

// fully-coherent (bypass L1+L2, served at coherence point) 16B ops — PROVEN
// pair (round 5 passed repeatedly with these for the h exchange).
__device__ __forceinline__ bf16x8 cohload16(const u16* p) {
  bf16x8 v;
  asm volatile("global_load_dwordx4 %0, %1, off sc0 sc1" : "=v"(v) : "v"(p));
  return v;
}
__device__ __forceinline__ void cohstore16(u16* p, bf16x8 v) {
  asm volatile("global_store_dwordx4 %0, %1, off sc0 sc1" :: "v"(p), "v"(v) : "memory");
}
// L1-bypass load for staged data. Correct under EITHER sc0 semantics:
//  (A) sc0 bypasses L1 only -> reads local L2, which holds the write-through
//      import (fresh).  (B) sc0 bypasses L2 too -> reads L3, which the
//      write-through import made fresh. Never reads L1.
__device__ __forceinline__ bf16x8 l2load16(const u16* p) {
  bf16x8 v;
  asm volatile("global_load_dwordx4 %0, %1, off sc0" : "=v"(v) : "v"(p));
  return v;
}
__device__ __forceinline__ int get_xcd() {
  int x;
  asm("s_getreg_b32 %0, hwreg(20, 0, 32)" : "=s"(x));   // HW_REG_XCC_ID (gfx940+)
  return x & 7;
}

// ---- preps ----
__global__ void conv_wih_kernel(const float* __restrict__ W, u16* __restrict__ Wb) {
  size_t idx = (size_t)blockIdx.x * blockDim.x + threadIdx.x;
  if (idx >= (size_t)GG * DD / 8) return;
  *(bf16x8*)(Wb + idx * 8) = cvt8(W + idx * 8);
}

// x: [B][T][D] fp32 -> xbT: [T][B][D] bf16
__global__ void conv_xT_kernel(const float* __restrict__ x, u16* __restrict__ xbT) {
  size_t idx = (size_t)blockIdx.x * blockDim.x + threadIdx.x;
  if (idx >= (size_t)BB * TT * DD / 8) return;
  const int col8 = (int)(idx & 127);
  const int row = (int)(idx >> 7);          // b*512 + t
  const int b = row >> 9, t = row & 511;
  bf16x8 v = cvt8(x + (size_t)row * DD + col8 * 8);
  *(bf16x8*)(xbT + ((size_t)t * BB + b) * DD + col8 * 8) = v;
}

// ======================= persistent LSTM =======================
// 256 WGs x 512 thr, 1 WG/CU (forced by 146 KB LDS => exactly 32 WGs per XCD).
// Cross-XCD h: producers cohstore h once; per XCD, each of the 32 WGs imports
// an 8 KB chunk and re-stores it WRITE-THROUGH (sc0 sc1) into a per-XCD staged
// copy (updates local L2 + L3 both fresh); a per-XCD agent-atomic counter
// (proven primitive) gates consumption; consumers read staged with sc0 loads.
template<int XMODE>   // 1: x from xbT [T,B,D] bf16; 0: x fp32 [B,T,D] direct
__global__ __launch_bounds__(512, 1)
void lstm_persistent(const float* __restrict__ x, const u16* __restrict__ xbT,
                     const u16* __restrict__ wihb, const float* __restrict__ W_hh,
                     const float* __restrict__ b_ih, const float* __restrict__ b_hh,
                     u16* __restrict__ h0, u16* __restrict__ h1,
                     int* __restrict__ arrv, int* __restrict__ gof,
                     int* __restrict__ ximp, int* __restrict__ xcdcnt,
                     u16* __restrict__ staged) {
  __shared__ u16 Wlds[64 * 2 * 64 * 8];   // 128 KB  [kb][which][lane][8]
  __shared__ float red[4 * 2 * 64 * 4];   // 8 KB
  __shared__ float gst[64 * 36];          // 9 KB (padded rows)
  __shared__ u16 hsh[512];                // 1 KB staging for coherent h store
  __shared__ int sxcd, srank;

  const int tid = threadIdx.x;
  const int wave = tid >> 6, lane = tid & 63;
  const int m = wave & 3, khalf = wave >> 2;
  const int c = lane & 15, g = lane >> 4;
  const int wg = blockIdx.x, j0 = wg * 8;

  // ---- one-time: physical-XCD detection + rank election (agent atomics) ----
  if (tid == 0) {
    const int xd = get_xcd();
    sxcd = xd;
    srank = __hip_atomic_fetch_add(xcdcnt + xd * 16, 1, __ATOMIC_RELAXED,
                                   __HIP_MEMORY_SCOPE_AGENT);
  }

  // ---- one-time: W_hh slice -> LDS in MFMA fragment order ----
  {
    const int r = tid >> 4;              // local row 0..31 (i,f,g,o x 8)
    const int gr = (r < 8) ? (j0 + r) : (r < 16) ? (HH + j0 + r - 8)
                 : (r < 24) ? (2 * HH + j0 + r - 16) : (3 * HH + j0 + r - 24);
    const int which = r >> 4, cc = r & 15;
    const float* src = W_hh + (size_t)gr * HH;
    const int k0 = (tid & 15) * 128;
    #pragma unroll
    for (int k8 = 0; k8 < 16; ++k8) {
      const int k = k0 + k8 * 8;
      bf16x8 v = cvt8(src + k);
      const int ent = ((k >> 5) * 2 + which) * 64 + ((k >> 3) & 3) * 16 + cc;
      *(bf16x8*)(Wlds + (size_t)ent * 8) = v;
    }
  }

  const int tb = tid >> 3, tj = tid & 7;
  const int jg = j0 + tj;
  const float bia = b_ih[jg] + b_hh[jg];
  const float bfa = b_ih[HH + jg] + b_hh[HH + jg];
  const float bga = b_ih[2 * HH + jg] + b_hh[2 * HH + jg];
  const float boa = b_ih[3 * HH + jg] + b_hh[3 * HH + jg];
  float cst = 0.f;

  const int arow = m * 16 + c;
  const int r0 = (c < 8) ? (j0 + c) : (HH + j0 + c - 8);          // i | f rows
  const int r1 = (c < 8) ? (2 * HH + j0 + c) : (3 * HH + j0 + c - 8); // g | o rows

  __syncthreads();
  const int xcd = sxcd, rank = srank & 31;
  int* xctr = ximp + xcd * 16;            // this XCD's import counter (64B pad)

  for (int t = 0; t < TT; ++t) {
    const u16* hs = (t & 1) ? h1 : h0;
    u16* hd = (t & 1) ? h0 : h1;
    u16* stg = staged + ((size_t)xcd * 2 + (t & 1)) * ((size_t)BB * HH);
    f32x4 acc0 = {0.f, 0.f, 0.f, 0.f};
    f32x4 acc1 = {0.f, 0.f, 0.f, 0.f};

    // ---- x-part (independent of h_{t-1}; overlaps barrier propagation) ----
    #pragma unroll 4
    for (int i = 0; i < 16; ++i) {
      const int k = khalf * 512 + i * 32 + g * 8;
      bf16x8 a;
      if constexpr (XMODE == 1) a = *(const bf16x8*)(xbT + ((size_t)t * BB + arow) * DD + k);
      else                      a = cvt8(x + ((size_t)arow * TT + t) * DD + k);
      bf16x8 b0 = *(const bf16x8*)(wihb + (size_t)r0 * DD + k);
      bf16x8 b1 = *(const bf16x8*)(wihb + (size_t)r1 * DD + k);
      acc0 = __builtin_amdgcn_mfma_f32_16x16x32_bf16(a, b0, acc0, 0, 0, 0);
      acc1 = __builtin_amdgcn_mfma_f32_16x16x32_bf16(a, b1, acc1, 0, 0, 0);
    }

    // ---- global barrier: all WGs finished step t-1 (proven protocol) ----
    if (t > 0) {
      if (wg == 0) {
        if (tid < 256) {
          int iters = 0;
          while (__hip_atomic_load(arrv + tid * 16, __ATOMIC_RELAXED, __HIP_MEMORY_SCOPE_AGENT) < t) {
            __builtin_amdgcn_s_sleep(1);
            if (++iters > (1 << 17)) break;   // fail loud, never hang
          }
        }
        __syncthreads();
        if (tid < 256)
          __hip_atomic_store(gof + tid * 16, t, __ATOMIC_RELAXED, __HIP_MEMORY_SCOPE_AGENT);
      } else {
        if (tid == 0) {
          int iters = 0;
          while (__hip_atomic_load(gof + wg * 16, __ATOMIC_RELAXED, __HIP_MEMORY_SCOPE_AGENT) < t) {
            __builtin_amdgcn_s_sleep(1);
            if (++iters > (1 << 17)) break;
          }
        }
      }
    }
    __syncthreads();

    // ---- import: this WG's 8 KB chunk (2 batch rows) -> XCD staged copy ----
    {
      const int row = rank * 2 + (tid >> 8);
      const int col = (tid & 255) * 8;
      bf16x8 v = cohload16(hs + (size_t)row * HH + col);
      asm volatile("s_waitcnt vmcnt(0)" ::: "memory");
      cohstore16(stg + (size_t)row * HH + col, v);   // write-through: L2+L3 fresh
      asm volatile("s_waitcnt vmcnt(0)" ::: "memory");
    }
    __syncthreads();
    if (tid == 0) {
      __hip_atomic_fetch_add(xctr, 1, __ATOMIC_RELAXED, __HIP_MEMORY_SCOPE_AGENT);
      int iters = 0;
      while (__hip_atomic_load(xctr, __ATOMIC_RELAXED, __HIP_MEMORY_SCOPE_AGENT) < 32 * (t + 1)) {
        __builtin_amdgcn_s_sleep(1);
        if (++iters > (1 << 17)) break;
      }
    }
    __syncthreads();

    // ---- h-part: 32x16B burst from staged (L1-bypassed), staged consume ----
    {
      bf16x8 hf[32];
      const u16* hrow = stg + (size_t)arow * HH + g * 8;
      #pragma unroll
      for (int i = 0; i < 32; ++i)
        hf[i] = l2load16(hrow + (size_t)(khalf * 32 + i) * 32);

      #pragma unroll
      for (int grp = 0; grp < 4; ++grp) {
        if (grp == 0)      asm volatile("s_waitcnt vmcnt(24)" ::: "memory");
        else if (grp == 1) asm volatile("s_waitcnt vmcnt(16)" ::: "memory");
        else if (grp == 2) asm volatile("s_waitcnt vmcnt(8)"  ::: "memory");
        else               asm volatile("s_waitcnt vmcnt(0)"  ::: "memory");
        __builtin_amdgcn_sched_barrier(0);
        #pragma unroll
        for (int i2 = 0; i2 < 8; ++i2) {
          const int i = grp * 8 + i2;
          const int kb = khalf * 32 + i;
          bf16x8 b0 = *(const bf16x8*)(Wlds + (size_t)((kb * 2 + 0) * 64 + lane) * 8);
          bf16x8 b1 = *(const bf16x8*)(Wlds + (size_t)((kb * 2 + 1) * 64 + lane) * 8);
          acc0 = __builtin_amdgcn_mfma_f32_16x16x32_bf16(hf[i], b0, acc0, 0, 0, 0);
          acc1 = __builtin_amdgcn_mfma_f32_16x16x32_bf16(hf[i], b1, acc1, 0, 0, 0);
        }
      }
    }

    // ---- reduce k-halves ----
    if (khalf == 1) {
      #pragma unroll
      for (int q = 0; q < 4; ++q) {
        red[((m * 2 + 0) * 64 + lane) * 4 + q] = acc0[q];
        red[((m * 2 + 1) * 64 + lane) * 4 + q] = acc1[q];
      }
    }
    __syncthreads();
    if (khalf == 0) {
      #pragma unroll
      for (int q = 0; q < 4; ++q) {
        const float s0 = acc0[q] + red[((m * 2 + 0) * 64 + lane) * 4 + q];
        const float s1 = acc1[q] + red[((m * 2 + 1) * 64 + lane) * 4 + q];
        const int b = m * 16 + g * 4 + q;
        gst[b * 36 + c] = s0;        // i (c<8) | f (c>=8)
        gst[b * 36 + 16 + c] = s1;   // g (c<8) | o (c>=8)
      }
    }
    __syncthreads();

    // ---- gates + state update (one (batch, j) pair per thread) ----
    {
      const float ip = gst[tb * 36 + tj]      + bia;
      const float fp = gst[tb * 36 + 8 + tj]  + bfa;
      const float gp = gst[tb * 36 + 16 + tj] + bga;
      const float op = gst[tb * 36 + 24 + tj] + boa;
      const float ig = 1.f / (1.f + expf(-ip));
      const float fg = 1.f / (1.f + expf(-fp));
      const float gv = tanhf(gp);
      const float og = 1.f / (1.f + expf(-op));
      cst = fg * cst + ig * gv;
      hsh[tb * 8 + tj] = f2bf(og * tanhf(cst));
    }
    __syncthreads();

    // ---- coherent h store (64 threads x 16B) + arrive ----
    if (tid < 64) {
      bf16x8 v = *(const bf16x8*)(hsh + tid * 8);
      cohstore16(hd + (size_t)tid * HH + j0, v);
      asm volatile("s_waitcnt vmcnt(0)" ::: "memory");   // data at coherence point
    }
    __syncthreads();
    if (tid == 0)
      __hip_atomic_store(arrv + wg * 16, t + 1, __ATOMIC_RELAXED, __HIP_MEMORY_SCOPE_AGENT);
  }
}

// ======================= fallback per-step kernel (round-1 proven) =======================
__global__ __launch_bounds__(512)
void lstm_step_kernel(const float* __restrict__ x,
                      const float* __restrict__ W_ih, const float* __restrict__ W_hh,
                      const float* __restrict__ b_ih, const float* __restrict__ b_hh,
                      const u16* __restrict__ h_src, u16* __restrict__ h_dst,
                      float* __restrict__ cbuf, int t) {
  const int tid = threadIdx.x;
  const int wave = tid >> 6, lane = tid & 63;
  const int m = wave & 3, khalf = wave >> 2;
  const int j0 = blockIdx.x * 8;
  const int c = lane & 15;
  const int arow = m * 16 + c;
  const int koff = (lane >> 4) * 8;
  const int r0 = (c < 8) ? (j0 + c) : (HH + j0 + c - 8);
  const int r1 = (c < 8) ? (2 * HH + j0 + c) : (3 * HH + j0 + c - 8);

  f32x4 acc0 = {0.f, 0.f, 0.f, 0.f};
  f32x4 acc1 = {0.f, 0.f, 0.f, 0.f};

  if (khalf == 0) {
    const size_t xrow = ((size_t)arow * TT + t) * DD;
    #pragma unroll 4
    for (int kb = 0; kb < 32; ++kb) {
      const int k = kb * 32 + koff;
      bf16x8 a = cvt8(x + xrow + k);
      bf16x8 b0 = cvt8(W_ih + (size_t)r0 * DD + k);
      bf16x8 b1 = cvt8(W_ih + (size_t)r1 * DD + k);
      acc0 = __builtin_amdgcn_mfma_f32_16x16x32_bf16(a, b0, acc0, 0, 0, 0);
      acc1 = __builtin_amdgcn_mfma_f32_16x16x32_bf16(a, b1, acc1, 0, 0, 0);
    }
    #pragma unroll 4
    for (int kb = 0; kb < 16; ++kb) {
      const int kh = kb * 32 + koff;
      bf16x8 a = *(const bf16x8*)(h_src + (size_t)arow * HH + kh);
      bf16x8 b0 = cvt8(W_hh + (size_t)r0 * HH + kh);
      bf16x8 b1 = cvt8(W_hh + (size_t)r1 * HH + kh);
      acc0 = __builtin_amdgcn_mfma_f32_16x16x32_bf16(a, b0, acc0, 0, 0, 0);
      acc1 = __builtin_amdgcn_mfma_f32_16x16x32_bf16(a, b1, acc1, 0, 0, 0);
    }
  } else {
    #pragma unroll 4
    for (int kb = 0; kb < 48; ++kb) {
      const int kh = 512 + kb * 32 + koff;
      bf16x8 a = *(const bf16x8*)(h_src + (size_t)arow * HH + kh);
      bf16x8 b0 = cvt8(W_hh + (size_t)r0 * HH + kh);
      bf16x8 b1 = cvt8(W_hh + (size_t)r1 * HH + kh);
      acc0 = __builtin_amdgcn_mfma_f32_16x16x32_bf16(a, b0, acc0, 0, 0, 0);
      acc1 = __builtin_amdgcn_mfma_f32_16x16x32_bf16(a, b1, acc1, 0, 0, 0);
    }
  }

  __shared__ float red[4][2][64][4];
  if (khalf == 1) {
    #pragma unroll
    for (int q = 0; q < 4; ++q) { red[m][0][lane][q] = acc0[q]; red[m][1][lane][q] = acc1[q]; }
  }
  __syncthreads();
  if (khalf == 1) return;
  #pragma unroll
  for (int q = 0; q < 4; ++q) { acc0[q] += red[m][0][lane][q]; acc1[q] += red[m][1][lane][q]; }

  const float bias0 = b_ih[r0] + b_hh[r0];
  const float bias1 = b_ih[r1] + b_hh[r1];
  #pragma unroll
  for (int q = 0; q < 4; ++q) { acc0[q] += bias0; acc1[q] += bias1; }

  float fpre[4], opre[4];
  #pragma unroll
  for (int q = 0; q < 4; ++q) {
    fpre[q] = __shfl_xor(acc0[q], 8);
    opre[q] = __shfl_xor(acc1[q], 8);
  }

  if (c < 8) {
    const int j = j0 + c;
    #pragma unroll
    for (int q = 0; q < 4; ++q) {
      const int b = m * 16 + (lane >> 4) * 4 + q;
      const float ig = 1.f / (1.f + expf(-acc0[q]));
      const float fg = 1.f / (1.f + expf(-fpre[q]));
      const float gg = tanhf(acc1[q]);
      const float og = 1.f / (1.f + expf(-opre[q]));
      const float cold = cbuf[(size_t)b * HH + j];
      const float cn = fg * cold + ig * gg;
      cbuf[(size_t)b * HH + j] = cn;
      h_dst[(size_t)b * HH + j] = f2bf(og * tanhf(cn));
    }
  }
}

// ======================= head =======================
__global__ __launch_bounds__(256)
void head_kernel(const u16* __restrict__ hfin, const float* __restrict__ W_head,
                 const float* __restrict__ b_head, float* __restrict__ out) {
  const int tid = threadIdx.x, wave = tid >> 6, lane = tid & 63;
  const int m = wave;
  const int c = lane & 15;
  const int koff = (lane >> 4) * 8;
  const int d = blockIdx.x * 16 + c;
  const int arow = m * 16 + c;
  f32x4 acc = {0.f, 0.f, 0.f, 0.f};
  #pragma unroll 4
  for (int kb = 0; kb < 64; ++kb) {
    const int k = kb * 32 + koff;
    bf16x8 a = *(const bf16x8*)(hfin + (size_t)arow * HH + k);
    bf16x8 b = cvt8(W_head + (size_t)d * HH + k);
    acc = __builtin_amdgcn_mfma_f32_16x16x32_bf16(a, b, acc, 0, 0, 0);
  }
  const float bh = b_head[d];
  #pragma unroll
  for (int q = 0; q < 4; ++q) {
    const int b = m * 16 + (lane >> 4) * 4 + q;
    out[(size_t)b * DD + d] = acc[q] + bh;
  }
}

extern "C" void kernel_launch(void* const* d_in, const int* in_sizes, int n_in,
                              void* d_out, int out_size, void* d_ws, size_t ws_size,
                              hipStream_t stream) {
  const float* x      = (const float*)d_in[0];
  const float* W_ih   = (const float*)d_in[1];
  const float* W_hh   = (const float*)d_in[2];
  const float* b_ih   = (const float*)d_in[3];
  const float* b_hh   = (const float*)d_in[4];
  const float* W_head = (const float*)d_in[5];
  const float* b_head = (const float*)d_in[6];
  float* out = (float*)d_out;

  char* ws = (char*)d_ws;
  u16*  h0     = (u16*)(ws + 0);                    // 256 KB
  u16*  h1     = (u16*)(ws + 256 * 1024);           // 256 KB
  int*  arrv   = (int*)(ws + 512 * 1024);           // 16 KB padded flags
  int*  gof    = (int*)(ws + 544 * 1024);           // 16 KB padded flags
  int*  ximp   = (int*)(ws + 576 * 1024);           // 8 per-XCD import counters
  int*  xcdcnt = (int*)(ws + 608 * 1024);           // 2 KB rank counters
  float* cbuf  = (float*)(ws + 512 * 1024);         // 512 KB (fallback mode only)
  u16*  staged = (u16*)(ws + (1ull << 20));         // 4 MB @ 1 MB (8 XCD x 2 x 256 KB)
  u16*  wihb   = (u16*)(ws + (5ull << 20));         // 16 MB @ 5 MB
  u16*  xbT    = (u16*)(ws + (21ull << 20));        // 64 MB @ 21 MB

  const size_t NEED1 = (85ull << 20);
  const size_t NEED0 = (21ull << 20);

  hipMemsetAsync(ws, 0, 1u << 20, stream);   // zero h0/h1/all flags every launch

  if (ws_size >= NEED0) {
    {
      const int n8 = (int)((size_t)GG * DD / 8);
      conv_wih_kernel<<<(n8 + 255) / 256, 256, 0, stream>>>(W_ih, wihb);
    }
    if (ws_size >= NEED1) {
      const int n8 = (int)((size_t)BB * TT * DD / 8);
      conv_xT_kernel<<<(n8 + 255) / 256, 256, 0, stream>>>(x, xbT);
      lstm_persistent<1><<<256, 512, 0, stream>>>(x, xbT, wihb, W_hh, b_ih, b_hh,
                                                  h0, h1, arrv, gof, ximp, xcdcnt, staged);
    } else {
      lstm_persistent<0><<<256, 512, 0, stream>>>(x, xbT, wihb, W_hh, b_ih, b_hh,
                                                  h0, h1, arrv, gof, ximp, xcdcnt, staged);
    }
  } else {
    for (int t = 0; t < TT; ++t) {
      u16* hs = (t & 1) ? h1 : h0;
      u16* hd = (t & 1) ? h0 : h1;
      lstm_step_kernel<<<256, 512, 0, stream>>>(x, W_ih, W_hh, b_ih, b_hh, hs, hd, cbuf, t);
    }
  }

  // t=511 (odd) -> final h in h0
  head_kernel<<<64, 256, 0, stream>>>(h0, W_head, b_head, out);
}

// Round 8
// 11762.745 us; speedup vs baseline: 1.0558x; 1.0558x over previous
//
#include <hip/hip_runtime.h>
#include <hip/hip_bf16.h>
#include <cstdint>
#include <cstddef>

#define BB 64
#define TT 512
#define DD 1024
#define HH 2048
#define GG 8192   // 4*H

typedef unsigned short u16;
typedef __attribute__((ext_vector_type(8))) short bf16x8;
typedef __attribute__((ext_vector_type(4))) float f32x4;

__device__ __forceinline__ u16 f2bf(float f) {
  union { float f; uint32_t u; } v; v.f = f;
  uint32_t r = v.u + 0x7FFFu + ((v.u >> 16) & 1u);  // RNE
  return (u16)(r >> 16);
}
__device__ __forceinline__ float bf2f(u16 h) {
  union { uint32_t u; float f; } v; v.u = ((uint32_t)h) << 16; return v.f;
}

__device__ __forceinline__ bf16x8 cvt8(const float* __restrict__ p) {
  float4 a = *(const float4*)p;
  float4 b = *(const float4*)(p + 4);
  bf16x8 r;
  r[0] = (short)f2bf(a.x); r[1] = (short)f2bf(a.y);
  r[2] = (short)f2bf(a.z); r[3] = (short)f2bf(a.w);
  r[4] = (short)f2bf(b.x); r[5] = (short)f2bf(b.y);
  r[6] = (short)f2bf(b.z); r[7] = (short)f2bf(b.w);
  return r;
}

// fully-coherent (bypass L1+L2, served at coherence point) 16B ops — PROVEN
__device__ __forceinline__ bf16x8 cohload16(const u16* p) {
  bf16x8 v;
  asm volatile("global_load_dwordx4 %0, %1, off sc0 sc1" : "=v"(v) : "v"(p));
  return v;
}
__device__ __forceinline__ void cohstore16(u16* p, bf16x8 v) {
  asm volatile("global_store_dwordx4 %0, %1, off sc0 sc1" :: "v"(p), "v"(v) : "memory");
}
__device__ __forceinline__ int get_xcd() {
  int x;
  asm("s_getreg_b32 %0, hwreg(20, 0, 32)" : "=s"(x));   // HW_REG_XCC_ID (gfx940+)
  return x & 7;
}

// ---- preps ----
__global__ void conv_wih_kernel(const float* __restrict__ W, u16* __restrict__ Wb) {
  size_t idx = (size_t)blockIdx.x * blockDim.x + threadIdx.x;
  if (idx >= (size_t)GG * DD / 8) return;
  *(bf16x8*)(Wb + idx * 8) = cvt8(W + idx * 8);
}

// x: [B][T][D] fp32 -> xbT: [T][B][D] bf16
__global__ void conv_xT_kernel(const float* __restrict__ x, u16* __restrict__ xbT) {
  size_t idx = (size_t)blockIdx.x * blockDim.x + threadIdx.x;
  if (idx >= (size_t)BB * TT * DD / 8) return;
  const int col8 = (int)(idx & 127);
  const int row = (int)(idx >> 7);          // b*512 + t
  const int b = row >> 9, t = row & 511;
  bf16x8 v = cvt8(x + (size_t)row * DD + col8 * 8);
  *(bf16x8*)(xbT + ((size_t)t * BB + b) * DD + col8 * 8) = v;
}

// ======================= persistent LSTM =======================
// 256 WGs x 512 thr, 1 WG/CU (forced by 146 KB LDS => exactly 32 WGs per XCD).
// Cross-XCD h: producers cohstore h (write-through to coherence point). Per
// XCD, each of the 32 WGs imports an 8 KB chunk with cohload and re-stores it
// with PLAIN stores -> dirty lines in the XCD's LOCAL L2 (no HBM writes).
// Per-XCD agent-atomic counter gates consumption. Consumers invalidate L1
// (`buffer_inv sc0`, cheap) then read staged with PLAIN loads -> local L2 hit.
template<int XMODE>   // 1: x from xbT [T,B,D] bf16; 0: x fp32 [B,T,D] direct
__global__ __launch_bounds__(512, 1)
void lstm_persistent(const float* __restrict__ x, const u16* __restrict__ xbT,
                     const u16* __restrict__ wihb, const float* __restrict__ W_hh,
                     const float* __restrict__ b_ih, const float* __restrict__ b_hh,
                     u16* __restrict__ h0, u16* __restrict__ h1,
                     int* __restrict__ arrv, int* __restrict__ gof,
                     int* __restrict__ ximp, int* __restrict__ xcdcnt,
                     u16* __restrict__ staged) {
  __shared__ u16 Wlds[64 * 2 * 64 * 8];   // 128 KB  [kb][which][lane][8]
  __shared__ float red[4 * 2 * 64 * 4];   // 8 KB
  __shared__ float gst[64 * 36];          // 9 KB (padded rows)
  __shared__ u16 hsh[512];                // 1 KB staging for coherent h store
  __shared__ int sxcd, srank;

  const int tid = threadIdx.x;
  const int wave = tid >> 6, lane = tid & 63;
  const int m = wave & 3, khalf = wave >> 2;
  const int c = lane & 15, g = lane >> 4;
  const int wg = blockIdx.x, j0 = wg * 8;

  // ---- one-time: physical-XCD detection + rank election (agent atomics) ----
  if (tid == 0) {
    const int xd = get_xcd();
    sxcd = xd;
    srank = __hip_atomic_fetch_add(xcdcnt + xd * 16, 1, __ATOMIC_RELAXED,
                                   __HIP_MEMORY_SCOPE_AGENT);
  }

  // ---- one-time: W_hh slice -> LDS in MFMA fragment order ----
  {
    const int r = tid >> 4;              // local row 0..31 (i,f,g,o x 8)
    const int gr = (r < 8) ? (j0 + r) : (r < 16) ? (HH + j0 + r - 8)
                 : (r < 24) ? (2 * HH + j0 + r - 16) : (3 * HH + j0 + r - 24);
    const int which = r >> 4, cc = r & 15;
    const float* src = W_hh + (size_t)gr * HH;
    const int k0 = (tid & 15) * 128;
    #pragma unroll
    for (int k8 = 0; k8 < 16; ++k8) {
      const int k = k0 + k8 * 8;
      bf16x8 v = cvt8(src + k);
      const int ent = ((k >> 5) * 2 + which) * 64 + ((k >> 3) & 3) * 16 + cc;
      *(bf16x8*)(Wlds + (size_t)ent * 8) = v;
    }
  }

  const int tb = tid >> 3, tj = tid & 7;
  const int jg = j0 + tj;
  const float bia = b_ih[jg] + b_hh[jg];
  const float bfa = b_ih[HH + jg] + b_hh[HH + jg];
  const float bga = b_ih[2 * HH + jg] + b_hh[2 * HH + jg];
  const float boa = b_ih[3 * HH + jg] + b_hh[3 * HH + jg];
  float cst = 0.f;

  const int arow = m * 16 + c;
  const int r0 = (c < 8) ? (j0 + c) : (HH + j0 + c - 8);          // i | f rows
  const int r1 = (c < 8) ? (2 * HH + j0 + c) : (3 * HH + j0 + c - 8); // g | o rows

  __syncthreads();
  const int xcd = sxcd, rank = srank & 31;
  int* xctr = ximp + xcd * 16;            // this XCD's import counter (64B pad)

  for (int t = 0; t < TT; ++t) {
    const u16* hs = (t & 1) ? h1 : h0;
    u16* hd = (t & 1) ? h0 : h1;
    u16* stg = staged + ((size_t)xcd * 2 + (t & 1)) * ((size_t)BB * HH);
    f32x4 acc0 = {0.f, 0.f, 0.f, 0.f};
    f32x4 acc1 = {0.f, 0.f, 0.f, 0.f};

    // ---- x-part (independent of h_{t-1}; overlaps barrier propagation) ----
    #pragma unroll 4
    for (int i = 0; i < 16; ++i) {
      const int k = khalf * 512 + i * 32 + g * 8;
      bf16x8 a;
      if constexpr (XMODE == 1) a = *(const bf16x8*)(xbT + ((size_t)t * BB + arow) * DD + k);
      else                      a = cvt8(x + ((size_t)arow * TT + t) * DD + k);
      bf16x8 b0 = *(const bf16x8*)(wihb + (size_t)r0 * DD + k);
      bf16x8 b1 = *(const bf16x8*)(wihb + (size_t)r1 * DD + k);
      acc0 = __builtin_amdgcn_mfma_f32_16x16x32_bf16(a, b0, acc0, 0, 0, 0);
      acc1 = __builtin_amdgcn_mfma_f32_16x16x32_bf16(a, b1, acc1, 0, 0, 0);
    }

    // ---- global barrier: all WGs finished step t-1 (proven protocol) ----
    if (t > 0) {
      if (wg == 0) {
        if (tid < 256) {
          int iters = 0;
          while (__hip_atomic_load(arrv + tid * 16, __ATOMIC_RELAXED, __HIP_MEMORY_SCOPE_AGENT) < t) {
            __builtin_amdgcn_s_sleep(1);
            if (++iters > (1 << 17)) break;   // fail loud, never hang
          }
        }
        __syncthreads();
        if (tid < 256)
          __hip_atomic_store(gof + tid * 16, t, __ATOMIC_RELAXED, __HIP_MEMORY_SCOPE_AGENT);
      } else {
        if (tid == 0) {
          int iters = 0;
          while (__hip_atomic_load(gof + wg * 16, __ATOMIC_RELAXED, __HIP_MEMORY_SCOPE_AGENT) < t) {
            __builtin_amdgcn_s_sleep(1);
            if (++iters > (1 << 17)) break;
          }
        }
      }
    }
    __syncthreads();

    // ---- import: 8 KB chunk (2 batch rows) -> XCD-local staged copy ----
    {
      const int row = rank * 2 + (tid >> 8);
      const int col = (tid & 255) * 8;
      bf16x8 v = cohload16(hs + (size_t)row * HH + col);
      asm volatile("s_waitcnt vmcnt(0)" ::: "memory");
      *(bf16x8*)(stg + (size_t)row * HH + col) = v;   // plain store -> dirty local L2
    }
    __syncthreads();   // drains vmcnt: all imports in L2 before counting
    if (tid == 0) {
      __hip_atomic_fetch_add(xctr, 1, __ATOMIC_RELAXED, __HIP_MEMORY_SCOPE_AGENT);
      int iters = 0;
      while (__hip_atomic_load(xctr, __ATOMIC_RELAXED, __HIP_MEMORY_SCOPE_AGENT) < 32 * (t + 1)) {
        __builtin_amdgcn_s_sleep(1);
        if (++iters > (1 << 17)) break;
      }
      // kill stale L1 lines for staged (L1-only invalidate: cheap, no L2 walk)
      asm volatile("buffer_inv sc0" ::: "memory");
      asm volatile("s_waitcnt vmcnt(0)" ::: "memory");
    }
    __syncthreads();

    // ---- h-part: plain loads from fresh local L2, MFMA consume ----
    {
      bf16x8 hf[32];
      const u16* hrow = stg + (size_t)arow * HH + g * 8;
      #pragma unroll
      for (int i = 0; i < 32; ++i)
        hf[i] = *(const bf16x8*)(hrow + (size_t)(khalf * 32 + i) * 32);
      #pragma unroll
      for (int i = 0; i < 32; ++i) {
        const int kb = khalf * 32 + i;
        bf16x8 b0 = *(const bf16x8*)(Wlds + (size_t)((kb * 2 + 0) * 64 + lane) * 8);
        bf16x8 b1 = *(const bf16x8*)(Wlds + (size_t)((kb * 2 + 1) * 64 + lane) * 8);
        acc0 = __builtin_amdgcn_mfma_f32_16x16x32_bf16(hf[i], b0, acc0, 0, 0, 0);
        acc1 = __builtin_amdgcn_mfma_f32_16x16x32_bf16(hf[i], b1, acc1, 0, 0, 0);
      }
    }

    // ---- reduce k-halves ----
    if (khalf == 1) {
      #pragma unroll
      for (int q = 0; q < 4; ++q) {
        red[((m * 2 + 0) * 64 + lane) * 4 + q] = acc0[q];
        red[((m * 2 + 1) * 64 + lane) * 4 + q] = acc1[q];
      }
    }
    __syncthreads();
    if (khalf == 0) {
      #pragma unroll
      for (int q = 0; q < 4; ++q) {
        const float s0 = acc0[q] + red[((m * 2 + 0) * 64 + lane) * 4 + q];
        const float s1 = acc1[q] + red[((m * 2 + 1) * 64 + lane) * 4 + q];
        const int b = m * 16 + g * 4 + q;
        gst[b * 36 + c] = s0;        // i (c<8) | f (c>=8)
        gst[b * 36 + 16 + c] = s1;   // g (c<8) | o (c>=8)
      }
    }
    __syncthreads();

    // ---- gates + state update (one (batch, j) pair per thread) ----
    {
      const float ip = gst[tb * 36 + tj]      + bia;
      const float fp = gst[tb * 36 + 8 + tj]  + bfa;
      const float gp = gst[tb * 36 + 16 + tj] + bga;
      const float op = gst[tb * 36 + 24 + tj] + boa;
      const float ig = 1.f / (1.f + expf(-ip));
      const float fg = 1.f / (1.f + expf(-fp));
      const float gv = tanhf(gp);
      const float og = 1.f / (1.f + expf(-op));
      cst = fg * cst + ig * gv;
      hsh[tb * 8 + tj] = f2bf(og * tanhf(cst));
    }
    __syncthreads();

    // ---- coherent h store (64 threads x 16B) + arrive (same wave) ----
    if (tid < 64) {
      bf16x8 v = *(const bf16x8*)(hsh + tid * 8);
      cohstore16(hd + (size_t)tid * HH + j0, v);
      asm volatile("s_waitcnt vmcnt(0)" ::: "memory");   // data at coherence point
    }
    if (tid == 0)
      __hip_atomic_store(arrv + wg * 16, t + 1, __ATOMIC_RELAXED, __HIP_MEMORY_SCOPE_AGENT);
  }
}

// ======================= fallback per-step kernel (round-1 proven) =======================
__global__ __launch_bounds__(512)
void lstm_step_kernel(const float* __restrict__ x,
                      const float* __restrict__ W_ih, const float* __restrict__ W_hh,
                      const float* __restrict__ b_ih, const float* __restrict__ b_hh,
                      const u16* __restrict__ h_src, u16* __restrict__ h_dst,
                      float* __restrict__ cbuf, int t) {
  const int tid = threadIdx.x;
  const int wave = tid >> 6, lane = tid & 63;
  const int m = wave & 3, khalf = wave >> 2;
  const int j0 = blockIdx.x * 8;
  const int c = lane & 15;
  const int arow = m * 16 + c;
  const int koff = (lane >> 4) * 8;
  const int r0 = (c < 8) ? (j0 + c) : (HH + j0 + c - 8);
  const int r1 = (c < 8) ? (2 * HH + j0 + c) : (3 * HH + j0 + c - 8);

  f32x4 acc0 = {0.f, 0.f, 0.f, 0.f};
  f32x4 acc1 = {0.f, 0.f, 0.f, 0.f};

  if (khalf == 0) {
    const size_t xrow = ((size_t)arow * TT + t) * DD;
    #pragma unroll 4
    for (int kb = 0; kb < 32; ++kb) {
      const int k = kb * 32 + koff;
      bf16x8 a = cvt8(x + xrow + k);
      bf16x8 b0 = cvt8(W_ih + (size_t)r0 * DD + k);
      bf16x8 b1 = cvt8(W_ih + (size_t)r1 * DD + k);
      acc0 = __builtin_amdgcn_mfma_f32_16x16x32_bf16(a, b0, acc0, 0, 0, 0);
      acc1 = __builtin_amdgcn_mfma_f32_16x16x32_bf16(a, b1, acc1, 0, 0, 0);
    }
    #pragma unroll 4
    for (int kb = 0; kb < 16; ++kb) {
      const int kh = kb * 32 + koff;
      bf16x8 a = *(const bf16x8*)(h_src + (size_t)arow * HH + kh);
      bf16x8 b0 = cvt8(W_hh + (size_t)r0 * HH + kh);
      bf16x8 b1 = cvt8(W_hh + (size_t)r1 * HH + kh);
      acc0 = __builtin_amdgcn_mfma_f32_16x16x32_bf16(a, b0, acc0, 0, 0, 0);
      acc1 = __builtin_amdgcn_mfma_f32_16x16x32_bf16(a, b1, acc1, 0, 0, 0);
    }
  } else {
    #pragma unroll 4
    for (int kb = 0; kb < 48; ++kb) {
      const int kh = 512 + kb * 32 + koff;
      bf16x8 a = *(const bf16x8*)(h_src + (size_t)arow * HH + kh);
      bf16x8 b0 = cvt8(W_hh + (size_t)r0 * HH + kh);
      bf16x8 b1 = cvt8(W_hh + (size_t)r1 * HH + kh);
      acc0 = __builtin_amdgcn_mfma_f32_16x16x32_bf16(a, b0, acc0, 0, 0, 0);
      acc1 = __builtin_amdgcn_mfma_f32_16x16x32_bf16(a, b1, acc1, 0, 0, 0);
    }
  }

  __shared__ float red[4][2][64][4];
  if (khalf == 1) {
    #pragma unroll
    for (int q = 0; q < 4; ++q) { red[m][0][lane][q] = acc0[q]; red[m][1][lane][q] = acc1[q]; }
  }
  __syncthreads();
  if (khalf == 1) return;
  #pragma unroll
  for (int q = 0; q < 4; ++q) { acc0[q] += red[m][0][lane][q]; acc1[q] += red[m][1][lane][q]; }

  const float bias0 = b_ih[r0] + b_hh[r0];
  const float bias1 = b_ih[r1] + b_hh[r1];
  #pragma unroll
  for (int q = 0; q < 4; ++q) { acc0[q] += bias0; acc1[q] += bias1; }

  float fpre[4], opre[4];
  #pragma unroll
  for (int q = 0; q < 4; ++q) {
    fpre[q] = __shfl_xor(acc0[q], 8);
    opre[q] = __shfl_xor(acc1[q], 8);
  }

  if (c < 8) {
    const int j = j0 + c;
    #pragma unroll
    for (int q = 0; q < 4; ++q) {
      const int b = m * 16 + (lane >> 4) * 4 + q;
      const float ig = 1.f / (1.f + expf(-acc0[q]));
      const float fg = 1.f / (1.f + expf(-fpre[q]));
      const float gg = tanhf(acc1[q]);
      const float og = 1.f / (1.f + expf(-opre[q]));
      const float cold = cbuf[(size_t)b * HH + j];
      const float cn = fg * cold + ig * gg;
      cbuf[(size_t)b * HH + j] = cn;
      h_dst[(size_t)b * HH + j] = f2bf(og * tanhf(cn));
    }
  }
}

// ======================= head =======================
__global__ __launch_bounds__(256)
void head_kernel(const u16* __restrict__ hfin, const float* __restrict__ W_head,
                 const float* __restrict__ b_head, float* __restrict__ out) {
  const int tid = threadIdx.x, wave = tid >> 6, lane = tid & 63;
  const int m = wave;
  const int c = lane & 15;
  const int koff = (lane >> 4) * 8;
  const int d = blockIdx.x * 16 + c;
  const int arow = m * 16 + c;
  f32x4 acc = {0.f, 0.f, 0.f, 0.f};
  #pragma unroll 4
  for (int kb = 0; kb < 64; ++kb) {
    const int k = kb * 32 + koff;
    bf16x8 a = *(const bf16x8*)(hfin + (size_t)arow * HH + k);
    bf16x8 b = cvt8(W_head + (size_t)d * HH + k);
    acc = __builtin_amdgcn_mfma_f32_16x16x32_bf16(a, b, acc, 0, 0, 0);
  }
  const float bh = b_head[d];
  #pragma unroll
  for (int q = 0; q < 4; ++q) {
    const int b = m * 16 + (lane >> 4) * 4 + q;
    out[(size_t)b * DD + d] = acc[q] + bh;
  }
}

extern "C" void kernel_launch(void* const* d_in, const int* in_sizes, int n_in,
                              void* d_out, int out_size, void* d_ws, size_t ws_size,
                              hipStream_t stream) {
  const float* x      = (const float*)d_in[0];
  const float* W_ih   = (const float*)d_in[1];
  const float* W_hh   = (const float*)d_in[2];
  const float* b_ih   = (const float*)d_in[3];
  const float* b_hh   = (const float*)d_in[4];
  const float* W_head = (const float*)d_in[5];
  const float* b_head = (const float*)d_in[6];
  float* out = (float*)d_out;

  char* ws = (char*)d_ws;
  u16*  h0     = (u16*)(ws + 0);                    // 256 KB
  u16*  h1     = (u16*)(ws + 256 * 1024);           // 256 KB
  int*  arrv   = (int*)(ws + 512 * 1024);           // 16 KB padded flags
  int*  gof    = (int*)(ws + 544 * 1024);           // 16 KB padded flags
  int*  ximp   = (int*)(ws + 576 * 1024);           // 8 per-XCD import counters
  int*  xcdcnt = (int*)(ws + 608 * 1024);           // 2 KB rank counters
  float* cbuf  = (float*)(ws + 512 * 1024);         // 512 KB (fallback mode only)
  u16*  staged = (u16*)(ws + (1ull << 20));         // 4 MB @ 1 MB (8 XCD x 2 x 256 KB)
  u16*  wihb   = (u16*)(ws + (5ull << 20));         // 16 MB @ 5 MB
  u16*  xbT    = (u16*)(ws + (21ull << 20));        // 64 MB @ 21 MB

  const size_t NEED1 = (85ull << 20);
  const size_t NEED0 = (21ull << 20);

  hipMemsetAsync(ws, 0, 1u << 20, stream);   // zero h0/h1/all flags every launch

  if (ws_size >= NEED0) {
    {
      const int n8 = (int)((size_t)GG * DD / 8);
      conv_wih_kernel<<<(n8 + 255) / 256, 256, 0, stream>>>(W_ih, wihb);
    }
    if (ws_size >= NEED1) {
      const int n8 = (int)((size_t)BB * TT * DD / 8);
      conv_xT_kernel<<<(n8 + 255) / 256, 256, 0, stream>>>(x, xbT);
      lstm_persistent<1><<<256, 512, 0, stream>>>(x, xbT, wihb, W_hh, b_ih, b_hh,
                                                  h0, h1, arrv, gof, ximp, xcdcnt, staged);
    } else {
      lstm_persistent<0><<<256, 512, 0, stream>>>(x, xbT, wihb, W_hh, b_ih, b_hh,
                                                  h0, h1, arrv, gof, ximp, xcdcnt, staged);
    }
  } else {
    for (int t = 0; t < TT; ++t) {
      u16* hs = (t & 1) ? h1 : h0;
      u16* hd = (t & 1) ? h0 : h1;
      lstm_step_kernel<<<256, 512, 0, stream>>>(x, W_ih, W_hh, b_ih, b_hh, hs, hd, cbuf, t);
    }
  }

  // t=511 (odd) -> final h in h0
  head_kernel<<<64, 256, 0, stream>>>(h0, W_head, b_head, out);
}

// Round 9
// 10408.694 us; speedup vs baseline: 1.1931x; 1.1301x over previous
//
#include <hip/hip_runtime.h>
#include <hip/hip_bf16.h>
#include <cstdint>
#include <cstddef>

#define BB 64
#define TT 512
#define DD 1024
#define HH 2048
#define GG 8192   // 4*H

typedef unsigned short u16;
typedef __attribute__((ext_vector_type(8))) short bf16x8;
typedef __attribute__((ext_vector_type(4))) float f32x4;

__device__ __forceinline__ u16 f2bf(float f) {
  union { float f; uint32_t u; } v; v.f = f;
  uint32_t r = v.u + 0x7FFFu + ((v.u >> 16) & 1u);  // RNE
  return (u16)(r >> 16);
}
__device__ __forceinline__ float bf2f(u16 h) {
  union { uint32_t u; float f; } v; v.u = ((uint32_t)h) << 16; return v.f;
}

__device__ __forceinline__ bf16x8 cvt8(const float* __restrict__ p) {
  float4 a = *(const float4*)p;
  float4 b = *(const float4*)(p + 4);
  bf16x8 r;
  r[0] = (short)f2bf(a.x); r[1] = (short)f2bf(a.y);
  r[2] = (short)f2bf(a.z); r[3] = (short)f2bf(a.w);
  r[4] = (short)f2bf(b.x); r[5] = (short)f2bf(b.y);
  r[6] = (short)f2bf(b.z); r[7] = (short)f2bf(b.w);
  return r;
}

// fully-coherent (bypass L1+L2, served at coherence point) 16B ops — PROVEN
__device__ __forceinline__ bf16x8 cohload16(const u16* p) {
  bf16x8 v;
  asm volatile("global_load_dwordx4 %0, %1, off sc0 sc1" : "=v"(v) : "v"(p));
  return v;
}
__device__ __forceinline__ void cohstore16(u16* p, bf16x8 v) {
  asm volatile("global_store_dwordx4 %0, %1, off sc0 sc1" :: "v"(p), "v"(v) : "memory");
}

// wave-wide poll of a monotone agent counter (all lanes same line -> one req)
__device__ __forceinline__ void wait_ctr(const int* ctr, int target) {
  int iters = 0;
  while (__hip_atomic_load(ctr, __ATOMIC_RELAXED, __HIP_MEMORY_SCOPE_AGENT) < target) {
    __builtin_amdgcn_s_sleep(1);
    if (++iters > (1 << 17)) break;   // fail loud, never hang
  }
  __builtin_amdgcn_sched_barrier(0);  // keep dependent loads below the poll
}

// ---- preps ----
__global__ void conv_wih_kernel(const float* __restrict__ W, u16* __restrict__ Wb) {
  size_t idx = (size_t)blockIdx.x * blockDim.x + threadIdx.x;
  if (idx >= (size_t)GG * DD / 8) return;
  *(bf16x8*)(Wb + idx * 8) = cvt8(W + idx * 8);
}

// x: [B][T][D] fp32 -> xbT: [T][B][D] bf16
__global__ void conv_xT_kernel(const float* __restrict__ x, u16* __restrict__ xbT) {
  size_t idx = (size_t)blockIdx.x * blockDim.x + threadIdx.x;
  if (idx >= (size_t)BB * TT * DD / 8) return;
  const int col8 = (int)(idx & 127);
  const int row = (int)(idx >> 7);          // b*512 + t
  const int b = row >> 9, t = row & 511;
  bf16x8 v = cvt8(x + (size_t)row * DD + col8 * 8);
  *(bf16x8*)(xbT + ((size_t)t * BB + b) * DD + col8 * 8) = v;
}

// ======================= persistent LSTM =======================
// 256 WGs x 512 thr, 1 WG/CU. WG owns h cols j0..j0+7 (32 gate rows).
// NO global barrier: 8 producer-group counters (32 WGs each, monotone).
// Producer: cohstore h chunk -> vmcnt(0) -> one agent atomicAdd.
// Consumer wave: poll the 4 group counters of its k-half (>= 32*t, rotated
// order), then cohload h directly (proven sc0sc1 path) + MFMA.
// Store-ack hidden: hsh parity double-buffer, no syncthreads after store.
template<int XMODE>   // 1: x from xbT [T,B,D] bf16; 0: x fp32 [B,T,D] direct
__global__ __launch_bounds__(512, 1)
void lstm_persistent(const float* __restrict__ x, const u16* __restrict__ xbT,
                     const u16* __restrict__ wihb, const float* __restrict__ W_hh,
                     const float* __restrict__ b_ih, const float* __restrict__ b_hh,
                     u16* __restrict__ h0, u16* __restrict__ h1,
                     int* __restrict__ gctr) {
  __shared__ u16 Wlds[64 * 2 * 64 * 8];   // 128 KB  [kb][which][lane][8]
  __shared__ float red[4 * 2 * 64 * 4];   // 8 KB
  __shared__ float gst[64 * 36];          // 9 KB (padded rows)
  __shared__ u16 hsh[2][512];             // 2 KB parity-double-buffered h stage

  const int tid = threadIdx.x;
  const int wave = tid >> 6, lane = tid & 63;
  const int m = wave & 3, khalf = wave >> 2;
  const int c = lane & 15, lofs = lane >> 4;
  const int wg = blockIdx.x, j0 = wg * 8;
  const int mygrp = wg >> 5;              // producer group (32 WGs / group)

  // ---- one-time: W_hh slice -> LDS in MFMA fragment order ----
  {
    const int r = tid >> 4;              // local row 0..31 (i,f,g,o x 8)
    const int gr = (r < 8) ? (j0 + r) : (r < 16) ? (HH + j0 + r - 8)
                 : (r < 24) ? (2 * HH + j0 + r - 16) : (3 * HH + j0 + r - 24);
    const int which = r >> 4, cc = r & 15;
    const float* src = W_hh + (size_t)gr * HH;
    const int k0 = (tid & 15) * 128;
    #pragma unroll
    for (int k8 = 0; k8 < 16; ++k8) {
      const int k = k0 + k8 * 8;
      bf16x8 v = cvt8(src + k);
      const int ent = ((k >> 5) * 2 + which) * 64 + ((k >> 3) & 3) * 16 + cc;
      *(bf16x8*)(Wlds + (size_t)ent * 8) = v;
    }
  }

  const int tb = tid >> 3, tj = tid & 7;
  const int jg = j0 + tj;
  const float bia = b_ih[jg] + b_hh[jg];
  const float bfa = b_ih[HH + jg] + b_hh[HH + jg];
  const float bga = b_ih[2 * HH + jg] + b_hh[2 * HH + jg];
  const float boa = b_ih[3 * HH + jg] + b_hh[3 * HH + jg];
  float cst = 0.f;

  const int arow = m * 16 + c;
  const int r0 = (c < 8) ? (j0 + c) : (HH + j0 + c - 8);          // i | f rows
  const int r1 = (c < 8) ? (2 * HH + j0 + c) : (3 * HH + j0 + c - 8); // g | o rows

  // poll order for this wave's 4 groups (rotated to spread contention)
  const int rot = wg & 3;
  const int pg0 = khalf * 4 + ((0 + rot) & 3);
  const int pg1 = khalf * 4 + ((1 + rot) & 3);
  const int pg2 = khalf * 4 + ((2 + rot) & 3);
  const int pg3 = khalf * 4 + ((3 + rot) & 3);

  __syncthreads();

  for (int t = 0; t < TT; ++t) {
    const u16* hs = (t & 1) ? h1 : h0;
    u16* hd = (t & 1) ? h0 : h1;
    f32x4 acc0 = {0.f, 0.f, 0.f, 0.f};
    f32x4 acc1 = {0.f, 0.f, 0.f, 0.f};

    // ---- x-part (h-independent; overlaps producers' tail of step t-1) ----
    #pragma unroll 4
    for (int i = 0; i < 16; ++i) {
      const int k = khalf * 512 + i * 32 + lofs * 8;
      bf16x8 a;
      if constexpr (XMODE == 1) a = *(const bf16x8*)(xbT + ((size_t)t * BB + arow) * DD + k);
      else                      a = cvt8(x + ((size_t)arow * TT + t) * DD + k);
      bf16x8 b0 = *(const bf16x8*)(wihb + (size_t)r0 * DD + k);
      bf16x8 b1 = *(const bf16x8*)(wihb + (size_t)r1 * DD + k);
      acc0 = __builtin_amdgcn_mfma_f32_16x16x32_bf16(a, b0, acc0, 0, 0, 0);
      acc1 = __builtin_amdgcn_mfma_f32_16x16x32_bf16(a, b1, acc1, 0, 0, 0);
    }

    // ---- fine-grained data gate: this wave's 4 producer groups ----
    if (t > 0) {
      const int tgt = 32 * t;
      wait_ctr(gctr + pg0 * 16, tgt);
      wait_ctr(gctr + pg1 * 16, tgt);
      wait_ctr(gctr + pg2 * 16, tgt);
      wait_ctr(gctr + pg3 * 16, tgt);
    }

    // ---- h-part: coherent 32x16B burst into registers, staged consume ----
    {
      bf16x8 hf[32];
      const u16* hrow = hs + (size_t)arow * HH + lofs * 8;
      #pragma unroll
      for (int i = 0; i < 32; ++i)
        hf[i] = cohload16(hrow + (size_t)(khalf * 32 + i) * 32);

      #pragma unroll
      for (int grp = 0; grp < 4; ++grp) {
        if (grp == 0)      asm volatile("s_waitcnt vmcnt(24)" ::: "memory");
        else if (grp == 1) asm volatile("s_waitcnt vmcnt(16)" ::: "memory");
        else if (grp == 2) asm volatile("s_waitcnt vmcnt(8)"  ::: "memory");
        else               asm volatile("s_waitcnt vmcnt(0)"  ::: "memory");
        __builtin_amdgcn_sched_barrier(0);
        #pragma unroll
        for (int i2 = 0; i2 < 8; ++i2) {
          const int i = grp * 8 + i2;
          const int kb = khalf * 32 + i;
          bf16x8 b0 = *(const bf16x8*)(Wlds + (size_t)((kb * 2 + 0) * 64 + lane) * 8);
          bf16x8 b1 = *(const bf16x8*)(Wlds + (size_t)((kb * 2 + 1) * 64 + lane) * 8);
          acc0 = __builtin_amdgcn_mfma_f32_16x16x32_bf16(hf[i], b0, acc0, 0, 0, 0);
          acc1 = __builtin_amdgcn_mfma_f32_16x16x32_bf16(hf[i], b1, acc1, 0, 0, 0);
        }
      }
    }

    // ---- reduce k-halves ----
    if (khalf == 1) {
      #pragma unroll
      for (int q = 0; q < 4; ++q) {
        red[((m * 2 + 0) * 64 + lane) * 4 + q] = acc0[q];
        red[((m * 2 + 1) * 64 + lane) * 4 + q] = acc1[q];
      }
    }
    __syncthreads();                                   // (A)
    if (khalf == 0) {
      #pragma unroll
      for (int q = 0; q < 4; ++q) {
        const float s0 = acc0[q] + red[((m * 2 + 0) * 64 + lane) * 4 + q];
        const float s1 = acc1[q] + red[((m * 2 + 1) * 64 + lane) * 4 + q];
        const int b = m * 16 + lofs * 4 + q;
        gst[b * 36 + c] = s0;        // i (c<8) | f (c>=8)
        gst[b * 36 + 16 + c] = s1;   // g (c<8) | o (c>=8)
      }
    }
    __syncthreads();                                   // (B)

    // ---- gates + state update (one (batch, j) pair per thread) ----
    {
      const float ip = gst[tb * 36 + tj]      + bia;
      const float fp = gst[tb * 36 + 8 + tj]  + bfa;
      const float gp = gst[tb * 36 + 16 + tj] + bga;
      const float op = gst[tb * 36 + 24 + tj] + boa;
      const float ig = 1.f / (1.f + expf(-ip));
      const float fg = 1.f / (1.f + expf(-fp));
      const float gv = tanhf(gp);
      const float og = 1.f / (1.f + expf(-op));
      cst = fg * cst + ig * gv;
      hsh[t & 1][tb * 8 + tj] = f2bf(og * tanhf(cst));
    }
    __syncthreads();                                   // (C)

    // ---- coherent h store (wave 0) + group flag; other waves run ahead ----
    if (tid < 64) {
      bf16x8 v = *(const bf16x8*)(&hsh[t & 1][tid * 8]);
      cohstore16(hd + (size_t)tid * HH + j0, v);
      asm volatile("s_waitcnt vmcnt(0)" ::: "memory");   // data at coherence point
    }
    if (tid == 0)
      __hip_atomic_fetch_add(gctr + mygrp * 16, 1, __ATOMIC_RELAXED,
                             __HIP_MEMORY_SCOPE_AGENT);
  }
}

// ======================= fallback per-step kernel (round-1 proven) =======================
__global__ __launch_bounds__(512)
void lstm_step_kernel(const float* __restrict__ x,
                      const float* __restrict__ W_ih, const float* __restrict__ W_hh,
                      const float* __restrict__ b_ih, const float* __restrict__ b_hh,
                      const u16* __restrict__ h_src, u16* __restrict__ h_dst,
                      float* __restrict__ cbuf, int t) {
  const int tid = threadIdx.x;
  const int wave = tid >> 6, lane = tid & 63;
  const int m = wave & 3, khalf = wave >> 2;
  const int j0 = blockIdx.x * 8;
  const int c = lane & 15;
  const int arow = m * 16 + c;
  const int koff = (lane >> 4) * 8;
  const int r0 = (c < 8) ? (j0 + c) : (HH + j0 + c - 8);
  const int r1 = (c < 8) ? (2 * HH + j0 + c) : (3 * HH + j0 + c - 8);

  f32x4 acc0 = {0.f, 0.f, 0.f, 0.f};
  f32x4 acc1 = {0.f, 0.f, 0.f, 0.f};

  if (khalf == 0) {
    const size_t xrow = ((size_t)arow * TT + t) * DD;
    #pragma unroll 4
    for (int kb = 0; kb < 32; ++kb) {
      const int k = kb * 32 + koff;
      bf16x8 a = cvt8(x + xrow + k);
      bf16x8 b0 = cvt8(W_ih + (size_t)r0 * DD + k);
      bf16x8 b1 = cvt8(W_ih + (size_t)r1 * DD + k);
      acc0 = __builtin_amdgcn_mfma_f32_16x16x32_bf16(a, b0, acc0, 0, 0, 0);
      acc1 = __builtin_amdgcn_mfma_f32_16x16x32_bf16(a, b1, acc1, 0, 0, 0);
    }
    #pragma unroll 4
    for (int kb = 0; kb < 16; ++kb) {
      const int kh = kb * 32 + koff;
      bf16x8 a = *(const bf16x8*)(h_src + (size_t)arow * HH + kh);
      bf16x8 b0 = cvt8(W_hh + (size_t)r0 * HH + kh);
      bf16x8 b1 = cvt8(W_hh + (size_t)r1 * HH + kh);
      acc0 = __builtin_amdgcn_mfma_f32_16x16x32_bf16(a, b0, acc0, 0, 0, 0);
      acc1 = __builtin_amdgcn_mfma_f32_16x16x32_bf16(a, b1, acc1, 0, 0, 0);
    }
  } else {
    #pragma unroll 4
    for (int kb = 0; kb < 48; ++kb) {
      const int kh = 512 + kb * 32 + koff;
      bf16x8 a = *(const bf16x8*)(h_src + (size_t)arow * HH + kh);
      bf16x8 b0 = cvt8(W_hh + (size_t)r0 * HH + kh);
      bf16x8 b1 = cvt8(W_hh + (size_t)r1 * HH + kh);
      acc0 = __builtin_amdgcn_mfma_f32_16x16x32_bf16(a, b0, acc0, 0, 0, 0);
      acc1 = __builtin_amdgcn_mfma_f32_16x16x32_bf16(a, b1, acc1, 0, 0, 0);
    }
  }

  __shared__ float red[4][2][64][4];
  if (khalf == 1) {
    #pragma unroll
    for (int q = 0; q < 4; ++q) { red[m][0][lane][q] = acc0[q]; red[m][1][lane][q] = acc1[q]; }
  }
  __syncthreads();
  if (khalf == 1) return;
  #pragma unroll
  for (int q = 0; q < 4; ++q) { acc0[q] += red[m][0][lane][q]; acc1[q] += red[m][1][lane][q]; }

  const float bias0 = b_ih[r0] + b_hh[r0];
  const float bias1 = b_ih[r1] + b_hh[r1];
  #pragma unroll
  for (int q = 0; q < 4; ++q) { acc0[q] += bias0; acc1[q] += bias1; }

  float fpre[4], opre[4];
  #pragma unroll
  for (int q = 0; q < 4; ++q) {
    fpre[q] = __shfl_xor(acc0[q], 8);
    opre[q] = __shfl_xor(acc1[q], 8);
  }

  if (c < 8) {
    const int j = j0 + c;
    #pragma unroll
    for (int q = 0; q < 4; ++q) {
      const int b = m * 16 + (lane >> 4) * 4 + q;
      const float ig = 1.f / (1.f + expf(-acc0[q]));
      const float fg = 1.f / (1.f + expf(-fpre[q]));
      const float gg = tanhf(acc1[q]);
      const float og = 1.f / (1.f + expf(-opre[q]));
      const float cold = cbuf[(size_t)b * HH + j];
      const float cn = fg * cold + ig * gg;
      cbuf[(size_t)b * HH + j] = cn;
      h_dst[(size_t)b * HH + j] = f2bf(og * tanhf(cn));
    }
  }
}

// ======================= head =======================
__global__ __launch_bounds__(256)
void head_kernel(const u16* __restrict__ hfin, const float* __restrict__ W_head,
                 const float* __restrict__ b_head, float* __restrict__ out) {
  const int tid = threadIdx.x, wave = tid >> 6, lane = tid & 63;
  const int m = wave;
  const int c = lane & 15;
  const int koff = (lane >> 4) * 8;
  const int d = blockIdx.x * 16 + c;
  const int arow = m * 16 + c;
  f32x4 acc = {0.f, 0.f, 0.f, 0.f};
  #pragma unroll 4
  for (int kb = 0; kb < 64; ++kb) {
    const int k = kb * 32 + koff;
    bf16x8 a = *(const bf16x8*)(hfin + (size_t)arow * HH + k);
    bf16x8 b = cvt8(W_head + (size_t)d * HH + k);
    acc = __builtin_amdgcn_mfma_f32_16x16x32_bf16(a, b, acc, 0, 0, 0);
  }
  const float bh = b_head[d];
  #pragma unroll
  for (int q = 0; q < 4; ++q) {
    const int b = m * 16 + (lane >> 4) * 4 + q;
    out[(size_t)b * DD + d] = acc[q] + bh;
  }
}

extern "C" void kernel_launch(void* const* d_in, const int* in_sizes, int n_in,
                              void* d_out, int out_size, void* d_ws, size_t ws_size,
                              hipStream_t stream) {
  const float* x      = (const float*)d_in[0];
  const float* W_ih   = (const float*)d_in[1];
  const float* W_hh   = (const float*)d_in[2];
  const float* b_ih   = (const float*)d_in[3];
  const float* b_hh   = (const float*)d_in[4];
  const float* W_head = (const float*)d_in[5];
  const float* b_head = (const float*)d_in[6];
  float* out = (float*)d_out;

  char* ws = (char*)d_ws;
  u16*  h0    = (u16*)(ws + 0);                    // 256 KB
  u16*  h1    = (u16*)(ws + 256 * 1024);           // 256 KB
  int*  gctr  = (int*)(ws + 512 * 1024);           // 8 padded group counters
  float* cbuf = (float*)(ws + 512 * 1024);         // 512 KB (fallback mode only)
  u16*  wihb  = (u16*)(ws + (1ull << 20));         // 16 MB @ 1 MB
  u16*  xbT   = (u16*)(ws + (17ull << 20));        // 64 MB @ 17 MB

  const size_t NEED1 = (81ull << 20);
  const size_t NEED0 = (17ull << 20);

  hipMemsetAsync(ws, 0, 1u << 20, stream);   // zero h0/h1/counters every launch

  if (ws_size >= NEED0) {
    {
      const int n8 = (int)((size_t)GG * DD / 8);
      conv_wih_kernel<<<(n8 + 255) / 256, 256, 0, stream>>>(W_ih, wihb);
    }
    if (ws_size >= NEED1) {
      const int n8 = (int)((size_t)BB * TT * DD / 8);
      conv_xT_kernel<<<(n8 + 255) / 256, 256, 0, stream>>>(x, xbT);
      lstm_persistent<1><<<256, 512, 0, stream>>>(x, xbT, wihb, W_hh, b_ih, b_hh,
                                                  h0, h1, gctr);
    } else {
      lstm_persistent<0><<<256, 512, 0, stream>>>(x, xbT, wihb, W_hh, b_ih, b_hh,
                                                  h0, h1, gctr);
    }
  } else {
    for (int t = 0; t < TT; ++t) {
      u16* hs = (t & 1) ? h1 : h0;
      u16* hd = (t & 1) ? h0 : h1;
      lstm_step_kernel<<<256, 512, 0, stream>>>(x, W_ih, W_hh, b_ih, b_hh, hs, hd, cbuf, t);
    }
  }

  // t=511 (odd) -> final h in h0
  head_kernel<<<64, 256, 0, stream>>>(h0, W_head, b_head, out);
}